// Round 2
// baseline (344.159 us; speedup 1.0000x reference)
//
#include <hip/hip_runtime.h>
#include <hip/hip_bf16.h>

#define DEV __device__ __forceinline__

constexpr int B_ = 16, CDIM = 256, NDIM = 4096, HID = 512, HEADS = 8, HC = 64;
constexpr float EPSV = 1e-5f;

using bf16x8 = __attribute__((ext_vector_type(8))) __bf16;
using f32x4  = __attribute__((ext_vector_type(4))) float;
using s16x8  = __attribute__((ext_vector_type(8))) short;

DEV short f2bf(float f) {
  __hip_bfloat16 h = __float2bfloat16(f);
  return *reinterpret_cast<short*>(&h);
}
DEV f32x4 MFMA(bf16x8 a, bf16x8 b, f32x4 c) {
  return __builtin_amdgcn_mfma_f32_16x16x32_bf16(a, b, c, 0, 0, 0);
}

// ---------------- weights -> bf16. Wall=[Wq;Wk;Wv] [1536][256]; Wo_b [256][512]
__global__ void wconv_kernel(const float* __restrict__ Wq, const float* __restrict__ Wk,
                             const float* __restrict__ Wv, const float* __restrict__ Wo,
                             short* __restrict__ Wall, short* __restrict__ Wo_b) {
  const int i = blockIdx.x * 256 + threadIdx.x;
  const int nw = HID * CDIM;  // 131072
  if (i < nw) Wall[i] = f2bf(Wq[i]);
  else if (i < 2 * nw) Wall[i] = f2bf(Wk[i - nw]);
  else if (i < 3 * nw) Wall[i] = f2bf(Wv[i - 2 * nw]);
  if (i < CDIM * HID) Wo_b[i] = f2bf(Wo[i]);
}

// ---------------- x [b][256][4096] f32 -> xt [b][4096][256] bf16
__global__ __launch_bounds__(256) void xconv_kernel(const float* __restrict__ x, short* __restrict__ xt) {
  __shared__ float t[32][33];
  const int bi = blockIdx.z, n0 = blockIdx.x * 32, c0 = blockIdx.y * 32;
  const int tx = threadIdx.x, ty = threadIdx.y;  // 32 x 8
  const float* xb = x + (size_t)bi * CDIM * NDIM;
#pragma unroll
  for (int i = 0; i < 32; i += 8)
    t[ty + i][tx] = xb[(size_t)(c0 + ty + i) * NDIM + n0 + tx];
  __syncthreads();
  short* xtb = xt + (size_t)bi * NDIM * CDIM;
#pragma unroll
  for (int i = 0; i < 32; i += 8)
    xtb[(size_t)(n0 + ty + i) * CDIM + c0 + tx] = f2bf(t[tx][ty + i]);
}

// ---------------- per (b,h,slice): on-the-fly k,v projection + online k-softmax + partial ctx
// block = 256 thr (4 waves). slice = 1024 n, chunks of 64 n.
// Wave w owns 16 d-rows (= e-rows for v) : wid*16 .. +16.
__global__ __launch_bounds__(256) void kvslice_kernel(const short* __restrict__ Wall,
                                                      const short* __restrict__ xt,
                                                      float* __restrict__ ctxp,
                                                      float* __restrict__ statp) {
  const int bh = blockIdx.x, sl = blockIdx.y;
  const int bi = bh >> 3, h = bh & 7;
  const int tid = threadIdx.x, lane = tid & 63, wid = tid >> 6;
  const int ro = lane & 15, ko = (lane >> 4) * 8;
  const short* Wk = Wall + (size_t)(HID + h * HC) * CDIM;
  const short* Wv = Wall + (size_t)(2 * HID + h * HC) * CDIM;
  const short* xb = xt + ((size_t)bi * NDIM + sl * 1024) * CDIM;

  __shared__ short xs[64][264];  // staged x rows [n][c], pad 8
  __shared__ short pl[64][72];   // p (softmaxed k) [d][n]
  __shared__ short vl[64][72];   // v [e][n]

  // preload Wk/Wv fragments for this wave's 16 rows
  bf16x8 ak[8], av[8];
#pragma unroll
  for (int ks = 0; ks < 8; ++ks) {
    ak[ks] = *(const bf16x8*)&Wk[(size_t)(wid * 16 + ro) * CDIM + ks * 32 + ko];
    av[ks] = *(const bf16x8*)&Wv[(size_t)(wid * 16 + ro) * CDIM + ks * 32 + ko];
  }
  float m[4], s[4];
#pragma unroll
  for (int j = 0; j < 4; ++j) { m[j] = -1e30f; s[j] = 0.f; }
  f32x4 cacc[4] = {};  // ctx rows d=wid*16+(lane>>4)*4+j, cols e=et*16+ro

  const int srow = tid >> 2, scol = (tid & 3) * 64;
  const int drow = wid * 16 + ((lane >> 4) << 2);

  for (int nc = 0; nc < 1024; nc += 64) {
    // stage 64 x-rows
#pragma unroll
    for (int i = 0; i < 8; ++i)
      *(s16x8*)&xs[srow][scol + i * 8] = *(const s16x8*)&xb[(size_t)(nc + srow) * CDIM + scol + i * 8];
    __syncthreads();
    // k tile [16 d][64 n] per wave
    f32x4 kacc[4] = {};
#pragma unroll
    for (int ks = 0; ks < 8; ++ks)
#pragma unroll
      for (int nt = 0; nt < 4; ++nt) {
        bf16x8 bfr = *(const bf16x8*)&xs[nt * 16 + ro][ks * 32 + ko];
        kacc[nt] = MFMA(ak[ks], bfr, kacc[nt]);
      }
    // online softmax update
    float mc[4];
#pragma unroll
    for (int j = 0; j < 4; ++j)
      mc[j] = fmaxf(fmaxf(kacc[0][j], kacc[1][j]), fmaxf(kacc[2][j], kacc[3][j]));
#pragma unroll
    for (int o = 1; o < 16; o <<= 1)
#pragma unroll
      for (int j = 0; j < 4; ++j) mc[j] = fmaxf(mc[j], __shfl_xor(mc[j], o));
    float scale[4];
#pragma unroll
    for (int j = 0; j < 4; ++j) {
      const float mn = fmaxf(m[j], mc[j]);
      scale[j] = __expf(m[j] - mn);
      m[j] = mn;
    }
    float ps[4] = {0.f, 0.f, 0.f, 0.f};
#pragma unroll
    for (int nt = 0; nt < 4; ++nt)
#pragma unroll
      for (int j = 0; j < 4; ++j) {
        const float p = __expf(kacc[nt][j] - m[j]);
        ps[j] += p;
        pl[drow + j][nt * 16 + ro] = f2bf(p);
      }
#pragma unroll
    for (int o = 1; o < 16; o <<= 1)
#pragma unroll
      for (int j = 0; j < 4; ++j) ps[j] += __shfl_xor(ps[j], o);
#pragma unroll
    for (int j = 0; j < 4; ++j) s[j] = s[j] * scale[j] + ps[j];
#pragma unroll
    for (int et = 0; et < 4; ++et)
#pragma unroll
      for (int j = 0; j < 4; ++j) cacc[et][j] *= scale[j];
    // v tile [16 e][64 n] per wave
    f32x4 vacc[4] = {};
#pragma unroll
    for (int ks = 0; ks < 8; ++ks)
#pragma unroll
      for (int nt = 0; nt < 4; ++nt) {
        bf16x8 bfr = *(const bf16x8*)&xs[nt * 16 + ro][ks * 32 + ko];
        vacc[nt] = MFMA(av[ks], bfr, vacc[nt]);
      }
#pragma unroll
    for (int nt = 0; nt < 4; ++nt)
#pragma unroll
      for (int j = 0; j < 4; ++j)
        vl[drow + j][nt * 16 + ro] = f2bf(vacc[nt][j]);
    __syncthreads();
    // ctx += p @ v^T over this chunk (K = 64 n)
#pragma unroll
    for (int ks = 0; ks < 2; ++ks) {
      bf16x8 pa = *(const bf16x8*)&pl[wid * 16 + ro][ks * 32 + ko];
#pragma unroll
      for (int et = 0; et < 4; ++et) {
        bf16x8 vb = *(const bf16x8*)&vl[et * 16 + ro][ks * 32 + ko];
        cacc[et] = MFMA(pa, vb, cacc[et]);
      }
    }
    __syncthreads();
  }
  // write raw partial ctx (fp32) + (m, s) stats
  float* cp = ctxp + ((size_t)bh * 4 + sl) * HC * HC;
#pragma unroll
  for (int et = 0; et < 4; ++et)
#pragma unroll
    for (int j = 0; j < 4; ++j)
      cp[(drow + j) * HC + et * 16 + ro] = cacc[et][j];
  if (ro == 0) {
    float* sp = statp + ((size_t)bh * 4 + sl) * HC * 2;
#pragma unroll
    for (int j = 0; j < 4; ++j) {
      sp[(drow + j) * 2] = m[j];
      sp[(drow + j) * 2 + 1] = s[j];
    }
  }
}

// ---------------- merge 4 n-slices -> ctx bf16 [bh][64][64]
__global__ __launch_bounds__(256) void ctxred_kernel(const float* __restrict__ ctxp,
                                                     const float* __restrict__ statp,
                                                     short* __restrict__ ctx) {
  const int bh = blockIdx.x, tid = threadIdx.x;
  const int d = tid >> 2, e0 = (tid & 3) * 16;
  const float* sp = statp + (size_t)bh * 4 * HC * 2;
  float m_i[4], s_i[4], mm = -1e30f;
#pragma unroll
  for (int i = 0; i < 4; ++i) {
    m_i[i] = sp[i * HC * 2 + d * 2];
    s_i[i] = sp[i * HC * 2 + d * 2 + 1];
    mm = fmaxf(mm, m_i[i]);
  }
  float w[4], stot = 0.f;
#pragma unroll
  for (int i = 0; i < 4; ++i) {
    w[i] = __expf(m_i[i] - mm);
    stot += s_i[i] * w[i];
  }
  const float inv = 1.f / stot;
  const float* cp = ctxp + (size_t)bh * 4 * HC * HC;
  short* cb = ctx + (size_t)bh * HC * HC;
  for (int e = e0; e < e0 + 16; ++e) {
    float u = 0.f;
#pragma unroll
    for (int i = 0; i < 4; ++i) u += cp[i * HC * HC + d * HC + e] * w[i];
    cb[d * HC + e] = f2bf(u * inv);
  }
}

// ---------------- Meff_b[o][h*64+d] = sum_e Wo[o][h*64+e] * ctx_bh[d][e]
__global__ __launch_bounds__(256) void meff_kernel(const short* __restrict__ Wo_b,
                                                   const short* __restrict__ ctx,
                                                   short* __restrict__ Meff) {
  const int bh = blockIdx.x, bi = bh >> 3, h = bh & 7;
  const int tid = threadIdx.x, lane = tid & 63, wid = tid >> 6;
  const int ro = lane & 15, ko = (lane >> 4) * 8;
  const short* Arow = Wo_b + h * HC;
  const short* Bc = ctx + (size_t)bh * HC * HC;
  f32x4 acc[4][4] = {};
#pragma unroll
  for (int ks = 0; ks < 64; ks += 32) {
    bf16x8 af[4], bv[4];
#pragma unroll
    for (int mi = 0; mi < 4; ++mi)
      af[mi] = *(const bf16x8*)&Arow[(size_t)(wid * 64 + mi * 16 + ro) * HID + ks + ko];
#pragma unroll
    for (int ni = 0; ni < 4; ++ni)
      bv[ni] = *(const bf16x8*)&Bc[(ni * 16 + ro) * HC + ks + ko];
#pragma unroll
    for (int mi = 0; mi < 4; ++mi)
#pragma unroll
      for (int ni = 0; ni < 4; ++ni) acc[mi][ni] = MFMA(af[mi], bv[ni], acc[mi][ni]);
  }
  short* Mb = Meff + (size_t)bi * CDIM * HID + h * HC;
  const int r0 = wid * 64 + ((lane >> 4) << 2), c0 = lane & 15;
#pragma unroll
  for (int mi = 0; mi < 4; ++mi)
#pragma unroll
    for (int ni = 0; ni < 4; ++ni)
#pragma unroll
      for (int j = 0; j < 4; ++j)
        Mb[(size_t)(r0 + mi * 16 + j) * HID + ni * 16 + c0] = f2bf(acc[mi][ni][j]);
}

// ---------------- fused q-proj + q-softmax(over 64 ch) + y = Meff_b @ qsoft + bias
// block = (b, ntile of 32 n). Wave w: phase1 cols w*128 (2 heads), phase2 o-rows w*64.
__global__ __launch_bounds__(256) void qy_kernel(const short* __restrict__ Wall,
                                                 const short* __restrict__ xt,
                                                 const short* __restrict__ Meff,
                                                 const float* __restrict__ bo,
                                                 float* __restrict__ out) {
  const int bi = blockIdx.y, n0 = blockIdx.x * 32;
  const int tid = threadIdx.x, lane = tid & 63, wid = tid >> 6;
  const int ro = lane & 15, ko = (lane >> 4) * 8;
  __shared__ short qs[32][520];  // qsoft^T [n][hd], pad 8
  const short* xb = xt + ((size_t)bi * NDIM + n0) * CDIM;
  // phase 1: qT[32 n][128 hd] per wave = xt_rows @ Wq_rows^T
  f32x4 qacc[2][8] = {};
#pragma unroll
  for (int ks = 0; ks < 8; ++ks) {
    bf16x8 af[2];
#pragma unroll
    for (int rt = 0; rt < 2; ++rt)
      af[rt] = *(const bf16x8*)&xb[(size_t)(rt * 16 + ro) * CDIM + ks * 32 + ko];
#pragma unroll
    for (int ct = 0; ct < 8; ++ct) {
      bf16x8 bfr = *(const bf16x8*)&Wall[(size_t)(wid * 128 + ct * 16 + ro) * CDIM + ks * 32 + ko];
#pragma unroll
      for (int rt = 0; rt < 2; ++rt) qacc[rt][ct] = MFMA(af[rt], bfr, qacc[rt][ct]);
    }
  }
  // per-head softmax over the 64 hd-channels (column-direction = within wave)
#pragma unroll
  for (int rt = 0; rt < 2; ++rt)
#pragma unroll
    for (int hl = 0; hl < 2; ++hl) {
      float mx[4];
#pragma unroll
      for (int j = 0; j < 4; ++j)
        mx[j] = fmaxf(fmaxf(qacc[rt][hl * 4][j], qacc[rt][hl * 4 + 1][j]),
                      fmaxf(qacc[rt][hl * 4 + 2][j], qacc[rt][hl * 4 + 3][j]));
#pragma unroll
      for (int o = 1; o < 16; o <<= 1)
#pragma unroll
        for (int j = 0; j < 4; ++j) mx[j] = fmaxf(mx[j], __shfl_xor(mx[j], o));
      float sm[4] = {0.f, 0.f, 0.f, 0.f};
      float pv[4][4];
#pragma unroll
      for (int c = 0; c < 4; ++c)
#pragma unroll
        for (int j = 0; j < 4; ++j) {
          pv[c][j] = __expf(qacc[rt][hl * 4 + c][j] - mx[j]);
          sm[j] += pv[c][j];
        }
#pragma unroll
      for (int o = 1; o < 16; o <<= 1)
#pragma unroll
        for (int j = 0; j < 4; ++j) sm[j] += __shfl_xor(sm[j], o);
#pragma unroll
      for (int j = 0; j < 4; ++j) sm[j] = 0.125f / sm[j];  // * HC^-0.5
#pragma unroll
      for (int c = 0; c < 4; ++c)
#pragma unroll
        for (int j = 0; j < 4; ++j)
          qs[rt * 16 + ((lane >> 4) << 2) + j][wid * 128 + (hl * 4 + c) * 16 + ro] =
              f2bf(pv[c][j] * sm[j]);
    }
  __syncthreads();
  // phase 2: y[o][n] = Meff @ qs^T ; wave w: 4 o-row-tiles x 2 n-col-tiles, K=512
  f32x4 yacc[4][2] = {};
  const short* Mb = Meff + (size_t)bi * CDIM * HID;
#pragma unroll
  for (int ks = 0; ks < 16; ++ks) {
    bf16x8 bq[2];
#pragma unroll
    for (int ct = 0; ct < 2; ++ct)
      bq[ct] = *(const bf16x8*)&qs[ct * 16 + ro][ks * 32 + ko];
#pragma unroll
    for (int rt = 0; rt < 4; ++rt) {
      bf16x8 am = *(const bf16x8*)&Mb[(size_t)(wid * 64 + rt * 16 + ro) * HID + ks * 32 + ko];
#pragma unroll
      for (int ct = 0; ct < 2; ++ct) yacc[rt][ct] = MFMA(am, bq[ct], yacc[rt][ct]);
    }
  }
  float* yb = out + (size_t)bi * CDIM * NDIM;
#pragma unroll
  for (int rt = 0; rt < 4; ++rt) {
    const int orow = wid * 64 + rt * 16 + ((lane >> 4) << 2);
#pragma unroll
    for (int j = 0; j < 4; ++j) {
      const float bias = bo[orow + j];
#pragma unroll
      for (int ct = 0; ct < 2; ++ct)
        yb[(size_t)(orow + j) * NDIM + n0 + ct * 16 + ro] = yacc[rt][ct][j] + bias;
    }
  }
}

// ---------------- GroupNorm stats (deterministic 2-stage)
__global__ __launch_bounds__(256) void stats_kernel(const float* __restrict__ y, float2* __restrict__ partials) {
  const int bi = blockIdx.y;
  const float4* y4 = (const float4*)(y + (size_t)bi * CDIM * NDIM);
  float s1 = 0.f, s2 = 0.f;
  for (int i = blockIdx.x * 256 + threadIdx.x; i < CDIM * NDIM / 4; i += 64 * 256) {
    float4 v = y4[i];
    s1 += v.x + v.y + v.z + v.w;
    s2 += v.x * v.x + v.y * v.y + v.z * v.z + v.w * v.w;
  }
  const int lane = threadIdx.x & 63, wid = threadIdx.x >> 6;
#pragma unroll
  for (int o = 32; o; o >>= 1) { s1 += __shfl_xor(s1, o); s2 += __shfl_xor(s2, o); }
  __shared__ float a1[4], a2[4];
  if (lane == 0) { a1[wid] = s1; a2[wid] = s2; }
  __syncthreads();
  if (threadIdx.x == 0)
    partials[bi * 64 + blockIdx.x] =
        make_float2(a1[0] + a1[1] + a1[2] + a1[3], a2[0] + a2[1] + a2[2] + a2[3]);
}

__global__ void redstats_kernel(const float2* __restrict__ partials, float* __restrict__ stats) {
  const int bi = blockIdx.x, l = threadIdx.x;  // 64 threads
  float2 p = partials[bi * 64 + l];
  float s1 = p.x, s2 = p.y;
#pragma unroll
  for (int o = 32; o; o >>= 1) { s1 += __shfl_xor(s1, o); s2 += __shfl_xor(s2, o); }
  if (l == 0) { stats[bi * 2] = s1; stats[bi * 2 + 1] = s2; }
}

// ---------------- normalize + affine + residual (in place on d_out)
__global__ __launch_bounds__(256) void final_kernel(float* __restrict__ y, const float* __restrict__ x,
                                                    const float* __restrict__ gamma, const float* __restrict__ beta,
                                                    const float* __restrict__ stats) {
  const int bi = blockIdx.y;
  constexpr float invN = 1.f / ((float)CDIM * NDIM);
  const float mean = stats[bi * 2] * invN;
  const float var = stats[bi * 2 + 1] * invN - mean * mean;
  const float rstd = rsqrtf(var + EPSV);
  float4* y4 = (float4*)(y + (size_t)bi * CDIM * NDIM);
  const float4* x4 = (const float4*)(x + (size_t)bi * CDIM * NDIM);
  for (int i = blockIdx.x * 256 + threadIdx.x; i < CDIM * NDIM / 4; i += 128 * 256) {
    const int c = i >> 10;
    const float g = gamma[c] * rstd;
    const float b = beta[c] - mean * g;
    float4 v = y4[i];
    const float4 xv = x4[i];
    v.x = v.x * g + b + xv.x;
    v.y = v.y * g + b + xv.y;
    v.z = v.z * g + b + xv.z;
    v.w = v.w * g + b + xv.w;
    y4[i] = v;
  }
}

extern "C" void kernel_launch(void* const* d_in, const int* in_sizes, int n_in,
                              void* d_out, int out_size, void* d_ws, size_t ws_size,
                              hipStream_t stream) {
  const float* x     = (const float*)d_in[0];
  const float* Wq    = (const float*)d_in[1];
  const float* Wk    = (const float*)d_in[2];
  const float* Wv    = (const float*)d_in[3];
  const float* Wo    = (const float*)d_in[4];
  const float* bo    = (const float*)d_in[5];
  const float* gamma = (const float*)d_in[6];
  const float* beta  = (const float*)d_in[7];
  float* out = (float*)d_out;

  char* w = (char*)d_ws;
  size_t off = 0;
  auto alloc = [&](size_t n) {
    char* p = w + off;
    off = (off + n + 255) & ~(size_t)255;
    return p;
  };
  short* xt    = (short*)alloc((size_t)B_ * NDIM * CDIM * 2);            // 33.5 MB
  short* Wall  = (short*)alloc((size_t)3 * HID * CDIM * 2);              // 0.79 MB
  short* Wo_b  = (short*)alloc((size_t)CDIM * HID * 2);                  // 0.26 MB
  float* ctxp  = (float*)alloc((size_t)128 * 4 * HC * HC * 4);           // 8.4 MB
  float* statp = (float*)alloc((size_t)128 * 4 * HC * 2 * 4);            // 0.26 MB
  short* ctx   = (short*)alloc((size_t)128 * HC * HC * 2);               // 1.0 MB
  short* Meff  = (short*)alloc((size_t)B_ * CDIM * HID * 2);             // 4.2 MB
  float2* partials = (float2*)alloc(1024 * sizeof(float2));
  float* stats = (float*)alloc(32 * 4);

  wconv_kernel<<<1536, 256, 0, stream>>>(Wq, Wk, Wv, Wo, Wall, Wo_b);
  xconv_kernel<<<dim3(128, 8, B_), dim3(32, 8), 0, stream>>>(x, xt);
  kvslice_kernel<<<dim3(128, 4), 256, 0, stream>>>(Wall, xt, ctxp, statp);
  ctxred_kernel<<<128, 256, 0, stream>>>(ctxp, statp, ctx);
  meff_kernel<<<128, 256, 0, stream>>>(Wo_b, ctx, Meff);
  qy_kernel<<<dim3(128, B_), 256, 0, stream>>>(Wall, xt, Meff, bo, out);
  stats_kernel<<<dim3(64, B_), 256, 0, stream>>>(out, partials);
  redstats_kernel<<<B_, 64, 0, stream>>>(partials, stats);
  final_kernel<<<dim3(128, B_), 256, 0, stream>>>(out, x, gamma, beta, stats);
}

// Round 3
// 342.306 us; speedup vs baseline: 1.0054x; 1.0054x over previous
//
#include <hip/hip_runtime.h>
#include <hip/hip_bf16.h>

#define DEV __device__ __forceinline__

constexpr int B_ = 16, CDIM = 256, NDIM = 4096, HID = 512, HEADS = 8, HC = 64;
constexpr float EPSV = 1e-5f;

using bf16x8 = __attribute__((ext_vector_type(8))) __bf16;
using f32x4  = __attribute__((ext_vector_type(4))) float;
using s16x8  = __attribute__((ext_vector_type(8))) short;

DEV short f2bf(float f) {
  __hip_bfloat16 h = __float2bfloat16(f);
  return *reinterpret_cast<short*>(&h);
}
DEV f32x4 MFMA(bf16x8 a, bf16x8 b, f32x4 c) {
  return __builtin_amdgcn_mfma_f32_16x16x32_bf16(a, b, c, 0, 0, 0);
}

// ---------------- weights -> bf16. Wall=[Wq;Wk;Wv] [1536][256]; Wo_b [256][512]
__global__ void wconv_kernel(const float* __restrict__ Wq, const float* __restrict__ Wk,
                             const float* __restrict__ Wv, const float* __restrict__ Wo,
                             short* __restrict__ Wall, short* __restrict__ Wo_b) {
  const int i = blockIdx.x * 256 + threadIdx.x;
  const int nw = HID * CDIM;  // 131072
  if (i < nw) Wall[i] = f2bf(Wq[i]);
  else if (i < 2 * nw) Wall[i] = f2bf(Wk[i - nw]);
  else if (i < 3 * nw) Wall[i] = f2bf(Wv[i - 2 * nw]);
  if (i < CDIM * HID) Wo_b[i] = f2bf(Wo[i]);
}

// ---------------- x [b][256][4096] f32 -> xt [b][4096][256] bf16
__global__ __launch_bounds__(256) void xconv_kernel(const float* __restrict__ x, short* __restrict__ xt) {
  __shared__ float t[32][33];
  const int bi = blockIdx.z, n0 = blockIdx.x * 32, c0 = blockIdx.y * 32;
  const int tx = threadIdx.x, ty = threadIdx.y;  // 32 x 8
  const float* xb = x + (size_t)bi * CDIM * NDIM;
#pragma unroll
  for (int i = 0; i < 32; i += 8)
    t[ty + i][tx] = xb[(size_t)(c0 + ty + i) * NDIM + n0 + tx];
  __syncthreads();
  short* xtb = xt + (size_t)bi * NDIM * CDIM;
#pragma unroll
  for (int i = 0; i < 32; i += 8)
    xtb[(size_t)(n0 + ty + i) * CDIM + c0 + tx] = f2bf(t[tx][ty + i]);
}

// ---------------- per (b,h,slice): on-the-fly k,v projection + online k-softmax + partial ctx
__global__ __launch_bounds__(256) void kvslice_kernel(const short* __restrict__ Wall,
                                                      const short* __restrict__ xt,
                                                      float* __restrict__ ctxp,
                                                      float* __restrict__ statp) {
  const int bh = blockIdx.x, sl = blockIdx.y;
  const int bi = bh >> 3, h = bh & 7;
  const int tid = threadIdx.x, lane = tid & 63, wid = tid >> 6;
  const int ro = lane & 15, ko = (lane >> 4) * 8;
  const short* Wk = Wall + (size_t)(HID + h * HC) * CDIM;
  const short* Wv = Wall + (size_t)(2 * HID + h * HC) * CDIM;
  const short* xb = xt + ((size_t)bi * NDIM + sl * 1024) * CDIM;

  __shared__ short xs[64][264];
  __shared__ short pl[64][72];
  __shared__ short vl[64][72];

  bf16x8 ak[8], av[8];
#pragma unroll
  for (int ks = 0; ks < 8; ++ks) {
    ak[ks] = *(const bf16x8*)&Wk[(size_t)(wid * 16 + ro) * CDIM + ks * 32 + ko];
    av[ks] = *(const bf16x8*)&Wv[(size_t)(wid * 16 + ro) * CDIM + ks * 32 + ko];
  }
  float m[4], s[4];
#pragma unroll
  for (int j = 0; j < 4; ++j) { m[j] = -1e30f; s[j] = 0.f; }
  f32x4 cacc[4] = {};

  const int srow = tid >> 2, scol = (tid & 3) * 64;
  const int drow = wid * 16 + ((lane >> 4) << 2);

  for (int nc = 0; nc < 1024; nc += 64) {
#pragma unroll
    for (int i = 0; i < 8; ++i)
      *(s16x8*)&xs[srow][scol + i * 8] = *(const s16x8*)&xb[(size_t)(nc + srow) * CDIM + scol + i * 8];
    __syncthreads();
    f32x4 kacc[4] = {};
#pragma unroll
    for (int ks = 0; ks < 8; ++ks)
#pragma unroll
      for (int nt = 0; nt < 4; ++nt) {
        bf16x8 bfr = *(const bf16x8*)&xs[nt * 16 + ro][ks * 32 + ko];
        kacc[nt] = MFMA(ak[ks], bfr, kacc[nt]);
      }
    float mc[4];
#pragma unroll
    for (int j = 0; j < 4; ++j)
      mc[j] = fmaxf(fmaxf(kacc[0][j], kacc[1][j]), fmaxf(kacc[2][j], kacc[3][j]));
#pragma unroll
    for (int o = 1; o < 16; o <<= 1)
#pragma unroll
      for (int j = 0; j < 4; ++j) mc[j] = fmaxf(mc[j], __shfl_xor(mc[j], o));
    float scale[4];
#pragma unroll
    for (int j = 0; j < 4; ++j) {
      const float mn = fmaxf(m[j], mc[j]);
      scale[j] = __expf(m[j] - mn);
      m[j] = mn;
    }
    float ps[4] = {0.f, 0.f, 0.f, 0.f};
#pragma unroll
    for (int nt = 0; nt < 4; ++nt)
#pragma unroll
      for (int j = 0; j < 4; ++j) {
        const float p = __expf(kacc[nt][j] - m[j]);
        ps[j] += p;
        pl[drow + j][nt * 16 + ro] = f2bf(p);
      }
#pragma unroll
    for (int o = 1; o < 16; o <<= 1)
#pragma unroll
      for (int j = 0; j < 4; ++j) ps[j] += __shfl_xor(ps[j], o);
#pragma unroll
    for (int j = 0; j < 4; ++j) s[j] = s[j] * scale[j] + ps[j];
#pragma unroll
    for (int et = 0; et < 4; ++et)
#pragma unroll
      for (int j = 0; j < 4; ++j) cacc[et][j] *= scale[j];
    f32x4 vacc[4] = {};
#pragma unroll
    for (int ks = 0; ks < 8; ++ks)
#pragma unroll
      for (int nt = 0; nt < 4; ++nt) {
        bf16x8 bfr = *(const bf16x8*)&xs[nt * 16 + ro][ks * 32 + ko];
        vacc[nt] = MFMA(av[ks], bfr, vacc[nt]);
      }
#pragma unroll
    for (int nt = 0; nt < 4; ++nt)
#pragma unroll
      for (int j = 0; j < 4; ++j)
        vl[drow + j][nt * 16 + ro] = f2bf(vacc[nt][j]);
    __syncthreads();
#pragma unroll
    for (int ks = 0; ks < 2; ++ks) {
      bf16x8 pa = *(const bf16x8*)&pl[wid * 16 + ro][ks * 32 + ko];
#pragma unroll
      for (int et = 0; et < 4; ++et) {
        bf16x8 vb = *(const bf16x8*)&vl[et * 16 + ro][ks * 32 + ko];
        cacc[et] = MFMA(pa, vb, cacc[et]);
      }
    }
    __syncthreads();
  }
  float* cp = ctxp + ((size_t)bh * 4 + sl) * HC * HC;
#pragma unroll
  for (int et = 0; et < 4; ++et)
#pragma unroll
    for (int j = 0; j < 4; ++j)
      cp[(drow + j) * HC + et * 16 + ro] = cacc[et][j];
  if (ro == 0) {
    float* sp = statp + ((size_t)bh * 4 + sl) * HC * 2;
#pragma unroll
    for (int j = 0; j < 4; ++j) {
      sp[(drow + j) * 2] = m[j];
      sp[(drow + j) * 2 + 1] = s[j];
    }
  }
}

// ---------------- merge 4 n-slices -> ctx bf16 [bh][64][64]
__global__ __launch_bounds__(256) void ctxred_kernel(const float* __restrict__ ctxp,
                                                     const float* __restrict__ statp,
                                                     short* __restrict__ ctx) {
  const int bh = blockIdx.x, tid = threadIdx.x;
  const int d = tid >> 2, e0 = (tid & 3) * 16;
  const float* sp = statp + (size_t)bh * 4 * HC * 2;
  float m_i[4], s_i[4], mm = -1e30f;
#pragma unroll
  for (int i = 0; i < 4; ++i) {
    m_i[i] = sp[i * HC * 2 + d * 2];
    s_i[i] = sp[i * HC * 2 + d * 2 + 1];
    mm = fmaxf(mm, m_i[i]);
  }
  float w[4], stot = 0.f;
#pragma unroll
  for (int i = 0; i < 4; ++i) {
    w[i] = __expf(m_i[i] - mm);
    stot += s_i[i] * w[i];
  }
  const float inv = 1.f / stot;
  const float* cp = ctxp + (size_t)bh * 4 * HC * HC;
  short* cb = ctx + (size_t)bh * HC * HC;
  for (int e = e0; e < e0 + 16; ++e) {
    float u = 0.f;
#pragma unroll
    for (int i = 0; i < 4; ++i) u += cp[i * HC * HC + d * HC + e] * w[i];
    cb[d * HC + e] = f2bf(u * inv);
  }
}

// ---------------- Meff_b[o][h*64+d] = sum_e Wo[o][h*64+e] * ctx_bh[d][e]
__global__ __launch_bounds__(256) void meff_kernel(const short* __restrict__ Wo_b,
                                                   const short* __restrict__ ctx,
                                                   short* __restrict__ Meff) {
  const int bh = blockIdx.x, bi = bh >> 3, h = bh & 7;
  const int tid = threadIdx.x, lane = tid & 63, wid = tid >> 6;
  const int ro = lane & 15, ko = (lane >> 4) * 8;
  const short* Arow = Wo_b + h * HC;
  const short* Bc = ctx + (size_t)bh * HC * HC;
  f32x4 acc[4][4] = {};
#pragma unroll
  for (int ks = 0; ks < 64; ks += 32) {
    bf16x8 af[4], bv[4];
#pragma unroll
    for (int mi = 0; mi < 4; ++mi)
      af[mi] = *(const bf16x8*)&Arow[(size_t)(wid * 64 + mi * 16 + ro) * HID + ks + ko];
#pragma unroll
    for (int ni = 0; ni < 4; ++ni)
      bv[ni] = *(const bf16x8*)&Bc[(ni * 16 + ro) * HC + ks + ko];
#pragma unroll
    for (int mi = 0; mi < 4; ++mi)
#pragma unroll
      for (int ni = 0; ni < 4; ++ni) acc[mi][ni] = MFMA(af[mi], bv[ni], acc[mi][ni]);
  }
  short* Mb = Meff + (size_t)bi * CDIM * HID + h * HC;
  const int r0 = wid * 64 + ((lane >> 4) << 2), c0 = lane & 15;
#pragma unroll
  for (int mi = 0; mi < 4; ++mi)
#pragma unroll
    for (int ni = 0; ni < 4; ++ni)
#pragma unroll
      for (int j = 0; j < 4; ++j)
        Mb[(size_t)(r0 + mi * 16 + j) * HID + ni * 16 + c0] = f2bf(acc[mi][ni][j]);
}

// ---------------- fused q-proj + q-softmax + y = Meff @ qsoft + bias + GN partial stats
// block: 64 n cols, 4 waves. Per head h (64 hd = one K-slice):
//   phase1: q-tile [16n/wave][64hd] from LDS-x (K=256); in-reg softmax; -> Bl LDS
//   phase2: acc2 += Meff[wid*64..][h*64..] @ Bl   (K=64)
__global__ __launch_bounds__(256) void qy_kernel(const short* __restrict__ Wall,
                                                 const short* __restrict__ xt,
                                                 const short* __restrict__ Meff,
                                                 const float* __restrict__ bo,
                                                 float* __restrict__ out,
                                                 float2* __restrict__ partials) {
  const int bi = blockIdx.y, n0 = blockIdx.x * 64;
  const int tid = threadIdx.x, lane = tid & 63, wid = tid >> 6;
  const int ro = lane & 15, ko = (lane >> 4) * 8;
  const int jr = (lane >> 4) << 2;
  __shared__ short xs[64][264];
  __shared__ short Bl[64][72];
  __shared__ float a1[4], a2[4];
  const short* xb = xt + ((size_t)bi * NDIM + n0) * CDIM;
  const int srow = tid >> 2, scol = (tid & 3) * 64;
#pragma unroll
  for (int i = 0; i < 8; ++i)
    *(s16x8*)&xs[srow][scol + i * 8] = *(const s16x8*)&xb[(size_t)srow * CDIM + scol + i * 8];
  __syncthreads();
  const short* Mb = Meff + (size_t)bi * CDIM * HID;
  f32x4 acc2[4][4] = {};
  for (int h = 0; h < HEADS; ++h) {
    const short* Wq = Wall + (size_t)(h * HC) * CDIM;
    f32x4 acc1[4] = {};
#pragma unroll
    for (int ks = 0; ks < 8; ++ks) {
      bf16x8 af = *(const bf16x8*)&xs[wid * 16 + ro][ks * 32 + ko];
#pragma unroll
      for (int ct = 0; ct < 4; ++ct) {
        bf16x8 bfr = *(const bf16x8*)&Wq[(size_t)(ct * 16 + ro) * CDIM + ks * 32 + ko];
        acc1[ct] = MFMA(af, bfr, acc1[ct]);
      }
    }
    // softmax over the 64 head-channels (4 ct in-thread x 16 ro lanes)
    float mx[4];
#pragma unroll
    for (int j = 0; j < 4; ++j)
      mx[j] = fmaxf(fmaxf(acc1[0][j], acc1[1][j]), fmaxf(acc1[2][j], acc1[3][j]));
#pragma unroll
    for (int o = 1; o < 16; o <<= 1)
#pragma unroll
      for (int j = 0; j < 4; ++j) mx[j] = fmaxf(mx[j], __shfl_xor(mx[j], o));
    float sm[4] = {0.f, 0.f, 0.f, 0.f};
    float pv[4][4];
#pragma unroll
    for (int ct = 0; ct < 4; ++ct)
#pragma unroll
      for (int j = 0; j < 4; ++j) {
        pv[ct][j] = __expf(acc1[ct][j] - mx[j]);
        sm[j] += pv[ct][j];
      }
#pragma unroll
    for (int o = 1; o < 16; o <<= 1)
#pragma unroll
      for (int j = 0; j < 4; ++j) sm[j] += __shfl_xor(sm[j], o);
#pragma unroll
    for (int j = 0; j < 4; ++j) sm[j] = 0.125f / sm[j];  // * HC^-0.5
#pragma unroll
    for (int ct = 0; ct < 4; ++ct)
#pragma unroll
      for (int j = 0; j < 4; ++j)
        Bl[wid * 16 + jr + j][ct * 16 + ro] = f2bf(pv[ct][j] * sm[j]);
    __syncthreads();
#pragma unroll
    for (int ks = 0; ks < 2; ++ks) {
      bf16x8 bq[4];
#pragma unroll
      for (int ct = 0; ct < 4; ++ct)
        bq[ct] = *(const bf16x8*)&Bl[ct * 16 + ro][ks * 32 + ko];
#pragma unroll
      for (int rt = 0; rt < 4; ++rt) {
        bf16x8 am = *(const bf16x8*)&Mb[(size_t)(wid * 64 + rt * 16 + ro) * HID + h * HC + ks * 32 + ko];
#pragma unroll
        for (int ct = 0; ct < 4; ++ct) acc2[rt][ct] = MFMA(am, bq[ct], acc2[rt][ct]);
      }
    }
    __syncthreads();
  }
  // epilogue: y write + GN partial stats
  float s1 = 0.f, s2 = 0.f;
  float* yb = out + (size_t)bi * CDIM * NDIM;
#pragma unroll
  for (int rt = 0; rt < 4; ++rt) {
    const int orow = wid * 64 + rt * 16 + jr;
#pragma unroll
    for (int j = 0; j < 4; ++j) {
      const float bias = bo[orow + j];
#pragma unroll
      for (int ct = 0; ct < 4; ++ct) {
        const float v = acc2[rt][ct][j] + bias;
        yb[(size_t)(orow + j) * NDIM + n0 + ct * 16 + ro] = v;
        s1 += v;
        s2 += v * v;
      }
    }
  }
#pragma unroll
  for (int o = 1; o < 64; o <<= 1) { s1 += __shfl_xor(s1, o); s2 += __shfl_xor(s2, o); }
  if (lane == 0) { a1[wid] = s1; a2[wid] = s2; }
  __syncthreads();
  if (tid == 0)
    partials[bi * 64 + blockIdx.x] =
        make_float2(a1[0] + a1[1] + a1[2] + a1[3], a2[0] + a2[1] + a2[2] + a2[3]);
}

__global__ void redstats_kernel(const float2* __restrict__ partials, float* __restrict__ stats) {
  const int bi = blockIdx.x, l = threadIdx.x;  // 64 threads
  float2 p = partials[bi * 64 + l];
  float s1 = p.x, s2 = p.y;
#pragma unroll
  for (int o = 32; o; o >>= 1) { s1 += __shfl_xor(s1, o); s2 += __shfl_xor(s2, o); }
  if (l == 0) { stats[bi * 2] = s1; stats[bi * 2 + 1] = s2; }
}

// ---------------- normalize + affine + residual (in place on d_out)
__global__ __launch_bounds__(256) void final_kernel(float* __restrict__ y, const float* __restrict__ x,
                                                    const float* __restrict__ gamma, const float* __restrict__ beta,
                                                    const float* __restrict__ stats) {
  const int bi = blockIdx.y;
  constexpr float invN = 1.f / ((float)CDIM * NDIM);
  const float mean = stats[bi * 2] * invN;
  const float var = stats[bi * 2 + 1] * invN - mean * mean;
  const float rstd = rsqrtf(var + EPSV);
  float4* y4 = (float4*)(y + (size_t)bi * CDIM * NDIM);
  const float4* x4 = (const float4*)(x + (size_t)bi * CDIM * NDIM);
  for (int i = blockIdx.x * 256 + threadIdx.x; i < CDIM * NDIM / 4; i += 128 * 256) {
    const int c = i >> 10;
    const float g = gamma[c] * rstd;
    const float b = beta[c] - mean * g;
    float4 v = y4[i];
    const float4 xv = x4[i];
    v.x = v.x * g + b + xv.x;
    v.y = v.y * g + b + xv.y;
    v.z = v.z * g + b + xv.z;
    v.w = v.w * g + b + xv.w;
    y4[i] = v;
  }
}

extern "C" void kernel_launch(void* const* d_in, const int* in_sizes, int n_in,
                              void* d_out, int out_size, void* d_ws, size_t ws_size,
                              hipStream_t stream) {
  const float* x     = (const float*)d_in[0];
  const float* Wq    = (const float*)d_in[1];
  const float* Wk    = (const float*)d_in[2];
  const float* Wv    = (const float*)d_in[3];
  const float* Wo    = (const float*)d_in[4];
  const float* bo    = (const float*)d_in[5];
  const float* gamma = (const float*)d_in[6];
  const float* beta  = (const float*)d_in[7];
  float* out = (float*)d_out;

  char* w = (char*)d_ws;
  size_t off = 0;
  auto alloc = [&](size_t n) {
    char* p = w + off;
    off = (off + n + 255) & ~(size_t)255;
    return p;
  };
  short* xt    = (short*)alloc((size_t)B_ * NDIM * CDIM * 2);            // 33.5 MB
  short* Wall  = (short*)alloc((size_t)3 * HID * CDIM * 2);              // 0.79 MB
  short* Wo_b  = (short*)alloc((size_t)CDIM * HID * 2);                  // 0.26 MB
  float* ctxp  = (float*)alloc((size_t)128 * 4 * HC * HC * 4);           // 8.4 MB
  float* statp = (float*)alloc((size_t)128 * 4 * HC * 2 * 4);            // 0.26 MB
  short* ctx   = (short*)alloc((size_t)128 * HC * HC * 2);               // 1.0 MB
  short* Meff  = (short*)alloc((size_t)B_ * CDIM * HID * 2);             // 4.2 MB
  float2* partials = (float2*)alloc(1024 * sizeof(float2));
  float* stats = (float*)alloc(32 * 4);

  wconv_kernel<<<1536, 256, 0, stream>>>(Wq, Wk, Wv, Wo, Wall, Wo_b);
  xconv_kernel<<<dim3(128, 8, B_), dim3(32, 8), 0, stream>>>(x, xt);
  kvslice_kernel<<<dim3(128, 4), 256, 0, stream>>>(Wall, xt, ctxp, statp);
  ctxred_kernel<<<128, 256, 0, stream>>>(ctxp, statp, ctx);
  meff_kernel<<<128, 256, 0, stream>>>(Wo_b, ctx, Meff);
  qy_kernel<<<dim3(64, B_), 256, 0, stream>>>(Wall, xt, Meff, bo, out, partials);
  redstats_kernel<<<B_, 64, 0, stream>>>(partials, stats);
  final_kernel<<<dim3(128, B_), 256, 0, stream>>>(out, x, gamma, beta, stats);
}